// Round 26
// baseline (87.763 us; speedup 1.0000x reference)
//
#include <hip/hip_runtime.h>

typedef __attribute__((ext_vector_type(4))) float f32x4;
typedef __attribute__((ext_vector_type(4))) unsigned u32x4;
typedef __attribute__((ext_vector_type(8))) short bf16x8;

constexpr int Bsz = 4096, Asz = 32, Isz = 256, Osz = 256;
constexpr int NIB = 4;                 // 32-row iterations per block (128 rows)

// packed f32x2 -> bf16x2 (RNE); no builtin on gfx950
__device__ inline unsigned cvtpk(float lo, float hi) {
    unsigned r;
    asm("v_cvt_pk_bf16_f32 %0, %1, %2" : "=v"(r) : "v"(lo), "v"(hi));
    return r;
}

// ---------------------------------------------------------------------------
// Pre-pack w [A,O,I] f32 -> bf16 fragment-linear: wf[((a*8+kt)*16+nf)*64+lane]
// = the 8 bf16 consumed by lane `lane` of B-fragment (a,kt,nf).
// o = nf*16 + (lane&15), i = kt*32 + (lane>>4)*8 .. +8   (r3-r13 proven)
// ---------------------------------------------------------------------------
__global__ __launch_bounds__(256) void pack_w(const float* __restrict__ w,
                                              unsigned short* __restrict__ wf) {
    const int gid  = blockIdx.x * 256 + threadIdx.x;
    const int lane = gid & 63, nf = (gid >> 6) & 15, kt = (gid >> 10) & 7, a = gid >> 13;
    const int o  = nf * 16 + (lane & 15);
    const int i0 = kt * 32 + (lane >> 4) * 8;
    const float* s = w + (size_t)(a * Osz + o) * Isz + i0;
    f32x4 lo = *(const f32x4*)s, hi = *(const f32x4*)(s + 4);
    union { bf16x8 v; unsigned u[4]; } r;
    r.u[0] = cvtpk(lo[0], lo[1]); r.u[1] = cvtpk(lo[2], lo[3]);
    r.u[2] = cvtpk(hi[0], hi[1]); r.u[3] = cvtpk(hi[2], hi[3]);
    *(bf16x8*)(wf + (size_t)gid * 8) = r.v;
}

// ---------------------------------------------------------------------------
// r26: trade LDS-resident B for TLP. 1024 blocks x 256 threads (4 waves),
// 4 blocks/CU = 16 waves/CU: four independent barrier domains per CU absorb
// barrier slack / fill latency / store drains (r25's 1-block convoy problem).
// B-frags read DIRECTLY from L2-resident packed wf at use-point (each wave
// reads only its own slice -- sB had no cross-wave sharing to lose); ~200cy
// latency covered by 4 waves/SIMD rotation. Block = (a, 128 rows): 4
// iterations of the proven r23 32-row pattern; sA 2x16KB bf16 (32 KB LDS);
// reg-staged A fill (1-deep; TLP covers); lgkmcnt(0)+raw barrier; NO vmcnt,
// NO DMA, NO B-hoist -- zero NaN-prone mechanisms.
// ---------------------------------------------------------------------------
__global__ __launch_bounds__(256, 4) void al_gemm(const float* __restrict__ x,
                                                  const unsigned short* __restrict__ wf,
                                                  const float* __restrict__ bias,
                                                  float* __restrict__ out)
{
    __shared__ char sA[2][16384];   // 32 rows x 512B bf16, chunk-XOR swizzled

    // 1024 blocks: xcd p&7 hosts a in {4k..4k+3}; 32 rowgroups of 128 rows.
    const int p  = blockIdx.x;
    const int a  = (p & 7) * 4 + ((p >> 3) & 3);
    const int b0 = (p >> 5) * 128;

    const int t    = threadIdx.x;
    const int w    = t >> 6;          // wave 0..3 = O-quarter (cols w*64..+63)
    const int lane = t & 63;
    const int llo  = lane & 15, lhi = lane >> 4;

    // ---- A fill (reg-staged): wave w covers tile rows 8w..8w+7.
    // lane -> row 8w+(lane>>3), f32 cols (lane&7)*32..+31 (8 f32x4 loads ->
    // 16 cvt_pk -> 4 ds_write_b128 at XOR-swizzled chunks).
    const int lr = 8 * w + (lane >> 3);
    const int c0 = (lane & 7) * 4;
    const float* xrow = x + ((size_t)(b0 + lr) * Asz + a) * Isz + (lane & 7) * 32;
    int wadr[4];
#pragma unroll
    for (int j = 0; j < 4; ++j)
        wadr[j] = lr * 512 + (((c0 + j) ^ (lr & 31)) << 4);
    const size_t STEP = (size_t)32 * Asz * Isz;

    f32x4 L[8];                       // in-flight fill regs (32 VGPR)

#define FISSUE(tn) {                                                           \
    const float* nx = xrow + (size_t)(tn) * STEP;                              \
    _Pragma("unroll")                                                          \
    for (int j = 0; j < 8; ++j) L[j] = *(const f32x4*)(nx + j * 4);            \
    asm volatile("" : "+v"(L[0]), "+v"(L[1]), "+v"(L[2]), "+v"(L[3]),          \
                      "+v"(L[4]), "+v"(L[5]), "+v"(L[6]), "+v"(L[7])); }

#define FWRITE(buf) {                                                          \
    char* Ad = &sA[buf][0];                                                    \
    _Pragma("unroll")                                                          \
    for (int j = 0; j < 4; ++j) {                                              \
        u32x4 pk;                                                              \
        pk[0] = cvtpk(L[2*j][0],   L[2*j][1]);                                 \
        pk[1] = cvtpk(L[2*j][2],   L[2*j][3]);                                 \
        pk[2] = cvtpk(L[2*j+1][0], L[2*j+1][1]);                               \
        pk[3] = cvtpk(L[2*j+1][2], L[2*j+1][3]);                               \
        *(u32x4*)&Ad[wadr[j]] = pk;                                            \
    } }

    // B direct from L2-resident wf: wave's 4 frags per kt
    const unsigned short* bp = wf + (size_t)a * 65536 + (w * 4) * 512 + lane * 8;

    float bv[4];
#pragma unroll
    for (int n = 0; n < 4; ++n) bv[n] = bias[a * Osz + w * 64 + n * 16 + llo];

    FISSUE(0);
    FWRITE(0);
    __syncthreads();   // sA[0] visible

    for (int tn = 0; tn < NIB; ++tn) {
        if (tn < NIB - 1) FISSUE(tn + 1);   // fill loads fly under compute

        const char* As = &sA[tn & 1][0];
        f32x4 acc[2][4];
#pragma unroll
        for (int m = 0; m < 2; ++m)
#pragma unroll
            for (int n = 0; n < 4; ++n) acc[m][n] = (f32x4)(bv[n]);

        __builtin_amdgcn_s_setprio(1);
#pragma unroll
        for (int kt = 0; kt < 8; ++kt) {
            bf16x8 bF[4];
#pragma unroll
            for (int n = 0; n < 4; ++n)      // issue all 4 L2 loads first
                bF[n] = *(const bf16x8*)(bp + (size_t)kt * 8192 + n * 512);
            const int r0 = llo, r1 = llo + 16;
            const bf16x8 aF0 = *(const bf16x8*)&As[r0 * 512 + (((kt * 4 + lhi) ^ (r0 & 31)) << 4)];
            const bf16x8 aF1 = *(const bf16x8*)&As[r1 * 512 + (((kt * 4 + lhi) ^ (r1 & 31)) << 4)];
#pragma unroll
            for (int n = 0; n < 4; ++n) {
                acc[0][n] = __builtin_amdgcn_mfma_f32_16x16x32_bf16(aF0, bF[n], acc[0][n], 0, 0, 0);
                acc[1][n] = __builtin_amdgcn_mfma_f32_16x16x32_bf16(aF1, bF[n], acc[1][n], 0, 0, 0);
            }
        }
        __builtin_amdgcn_s_setprio(0);

        // stores: D[row = tn*32 + m*16 + lhi*4 + r2][col = w*64 + n*16 + llo]
#pragma unroll
        for (int m = 0; m < 2; ++m) {
            const int trow = b0 + tn * 32 + m * 16 + lhi * 4;
            float* op = out + ((size_t)trow * Asz + a) * Osz + w * 64 + llo;
#pragma unroll
            for (int r2 = 0; r2 < 4; ++r2)
#pragma unroll
                for (int n = 0; n < 4; ++n)
                    op[(size_t)r2 * Asz * Osz + n * 16] = acc[m][n][r2];
        }

        if (tn < NIB - 1) {
            FWRITE((tn + 1) & 1);           // cvt + write next tile
            // ds_writes visible; stores/loads NOT drained (raw barrier).
            asm volatile("s_waitcnt lgkmcnt(0)" ::: "memory");
            __builtin_amdgcn_s_barrier();
        }
    }
#undef FISSUE
#undef FWRITE
}

extern "C" void kernel_launch(void* const* d_in, const int* in_sizes, int n_in,
                              void* d_out, int out_size, void* d_ws, size_t ws_size,
                              hipStream_t stream) {
    const float* x    = (const float*)d_in[0];
    const float* w    = (const float*)d_in[1];
    const float* bias = (const float*)d_in[2];
    float* out        = (float*)d_out;
    unsigned short* wf = (unsigned short*)d_ws;   // 4 MB

    pack_w<<<dim3(Asz * 8 * 16 * 64 / 256), dim3(256), 0, stream>>>(w, wf);
    al_gemm<<<dim3(1024), dim3(256), 0, stream>>>(x, wf, bias, out);
}

// Round 27
// 70.311 us; speedup vs baseline: 1.2482x; 1.2482x over previous
//
#include <hip/hip_runtime.h>

typedef __attribute__((ext_vector_type(4))) float f32x4;
typedef __attribute__((ext_vector_type(8))) short bf16x8;

constexpr int Asz = 32, Isz = 256, Osz = 256;

// packed f32x2 -> bf16x2 (RNE); no builtin on gfx950
__device__ inline unsigned cvtpk(float lo, float hi) {
    unsigned r;
    asm("v_cvt_pk_bf16_f32 %0, %1, %2" : "=v"(r) : "v"(lo), "v"(hi));
    return r;
}

// ---------------------------------------------------------------------------
// r27: barrier-free main loop. 256 blocks (1/CU), 512 threads = 8 waves,
// LDS = sB only (128 KB, w[a] packed bf16 fragment-linear, read-only after
// the single __syncthreads). Each wave owns DISJOINT rows x full O=256:
// per tile (16 rows), per kt: A-frag comes DIRECTLY from global via a 4-deep
// pinned register pipeline (lane's 8 contiguous f32 = the exact fragment;
// wave covers full 128B lines) -> cvt_pk -> 16 B ds_reads + 16 MFMAs.
// vs r25: sA deleted, ALL main-loop barriers deleted (waves free-run),
// total LDS reads unchanged (4096/CU), x read once. No vmcnt, no DMA,
// no B-hoist. acc = 16 frags (64 VGPR); launch_bounds(512,2) caps at 256.
// ---------------------------------------------------------------------------
__global__ __launch_bounds__(512, 2) void al_gemm(const float* __restrict__ x,
                                                  const float* __restrict__ wsrc,
                                                  const float* __restrict__ bias,
                                                  float* __restrict__ out)
{
    __shared__ char sB[131072];     // packed B, fragment-linear

    // 256 blocks: xcd p&7 hosts a in {4k..4k+3}; rowgroup p>>5 -> 512 rows.
    const int p  = blockIdx.x;
    const int a  = (p & 7) * 4 + ((p >> 3) & 3);
    const int b0 = (p >> 5) * 512;

    const int t    = threadIdx.x;
    const int w    = t >> 6;          // wave 0..7
    const int lane = t & 63;
    const int llo  = lane & 15, lhi = lane >> 4;

    // A: wave w, tile tt (0..3) covers rows b0 + (tt*8 + w)*16 .. +16.
    // Lane reads row base+llo at k = kt*32 + lhi*8 (8 contiguous f32 = frag).
    const float* pA = x + ((size_t)(b0 + w * 16 + llo) * Asz + a) * Isz + lhi * 8;
    const size_t TSTEP = (size_t)128 * Asz * Isz;   // 128 rows per tile round

    f32x4 L[4][2];   // 4-deep pipeline, 2 f32x4 per step (32 VGPR), static sets

#define AISSUE(set, off) {                                                     \
    L[set][0] = *(const f32x4*)(pA + (off));                                   \
    L[set][1] = *(const f32x4*)(pA + (off) + 4);                               \
    asm volatile("" : "+v"(L[set][0]), "+v"(L[set][1])); }

    // prologue: preload steps 0..3 (tile0, kt0..3) — they fly during the pack
    AISSUE(0, 0); AISSUE(1, 32); AISSUE(2, 64); AISSUE(3, 96);

    // ---- pack w[a] f32 -> sB bf16, fragment-linear — COALESCED (r19):
    // slot s = i*512+t -> 8 contiguous f32 at wa+s*8 = lane-slot of frag:
    // o = s>>5, kt = (s>>2)&7, nf = s>>9, lane_ = (o&15) | ((s&3)<<4).
    {
        const float* wa = wsrc + (size_t)a * (Osz * Isz);
#pragma unroll
        for (int i = 0; i < 16; ++i) {
            const int s     = i * 512 + t;
            const int o     = s >> 5;
            const int kt    = (s >> 2) & 7;
            const int nf    = s >> 9;
            const int lane_ = (o & 15) | ((s & 3) << 4);
            f32x4 lo = *(const f32x4*)(wa + (size_t)s * 8);
            f32x4 hi = *(const f32x4*)(wa + (size_t)s * 8 + 4);
            union { bf16x8 v; unsigned u[4]; } r;
            r.u[0] = cvtpk(lo[0], lo[1]); r.u[1] = cvtpk(lo[2], lo[3]);
            r.u[2] = cvtpk(hi[0], hi[1]); r.u[3] = cvtpk(hi[2], hi[3]);
            *(bf16x8*)&sB[(((kt * 16 + nf) * 64) + lane_) * 16] = r.v;
        }
    }

    float bv[16];
#pragma unroll
    for (int n = 0; n < 16; ++n) bv[n] = bias[a * Osz + n * 16 + llo];

    __syncthreads();   // sB visible — the ONLY barrier; waves free-run after

    for (int tt = 0; tt < 4; ++tt) {
        f32x4 acc[16];
#pragma unroll
        for (int n = 0; n < 16; ++n) acc[n] = (f32x4)(bv[n]);

#pragma unroll
        for (int kt = 0; kt < 8; ++kt) {
            const int set = kt & 3;
            // consume this step's loads (compiler inserts the vmcnt wait)
            union { bf16x8 v; unsigned u[4]; } r;
            r.u[0] = cvtpk(L[set][0][0], L[set][0][1]);
            r.u[1] = cvtpk(L[set][0][2], L[set][0][3]);
            r.u[2] = cvtpk(L[set][1][0], L[set][1][1]);
            r.u[3] = cvtpk(L[set][1][2], L[set][1][3]);
            const bf16x8 aF = r.v;

            // refill the freed set with step s+4 (4-step latency cover)
            if (kt < 4) {
                AISSUE(set, (size_t)tt * TSTEP + (kt + 4) * 32);
            } else if (tt < 3) {
                AISSUE(set, (size_t)(tt + 1) * TSTEP + (kt - 4) * 32);
            }

            __builtin_amdgcn_s_setprio(1);
#pragma unroll
            for (int n = 0; n < 16; ++n) {
                const bf16x8 bF = *(const bf16x8*)&sB[(kt * 16 + n) * 1024 + lane * 16];
                acc[n] = __builtin_amdgcn_mfma_f32_16x16x32_bf16(aF, bF, acc[n], 0, 0, 0);
            }
            __builtin_amdgcn_s_setprio(0);
        }

        // stores: D[row = (tt*8+w)*16 + lhi*4 + r2][col = n*16 + llo]
        const int trow = b0 + (tt * 8 + w) * 16 + lhi * 4;
        float* op = out + ((size_t)trow * Asz + a) * Osz + llo;
#pragma unroll
        for (int n = 0; n < 16; ++n)
#pragma unroll
            for (int r2 = 0; r2 < 4; ++r2)
                op[(size_t)r2 * Asz * Osz + n * 16] = acc[n][r2];
    }
#undef AISSUE
}

extern "C" void kernel_launch(void* const* d_in, const int* in_sizes, int n_in,
                              void* d_out, int out_size, void* d_ws, size_t ws_size,
                              hipStream_t stream) {
    const float* x    = (const float*)d_in[0];
    const float* w    = (const float*)d_in[1];
    const float* bias = (const float*)d_in[2];
    float* out        = (float*)d_out;
    al_gemm<<<dim3(256), dim3(512), 0, stream>>>(x, w, bias, out);
}

// Round 28
// 60.562 us; speedup vs baseline: 1.4491x; 1.1610x over previous
//
#include <hip/hip_runtime.h>

typedef __attribute__((ext_vector_type(4))) float f32x4;
typedef __attribute__((ext_vector_type(4))) unsigned u32x4;
typedef __attribute__((ext_vector_type(8))) short bf16x8;

constexpr int Asz = 32, Isz = 256, Osz = 256;
constexpr int NI = 32;                 // 16-row iterations (512 rows/block)

// packed f32x2 -> bf16x2 (RNE); no builtin on gfx950
__device__ inline unsigned cvtpk(float lo, float hi) {
    unsigned r;
    asm("v_cvt_pk_bf16_f32 %0, %1, %2" : "=v"(r) : "v"(lo), "v"(hi));
    return r;
}

// ---------------------------------------------------------------------------
// r28: O-SPLIT, 2 blocks/CU. Block = (a, 512 rows, O-half of 128 cols):
// sB = 64 KB (only this half's 8 nf-frags per kt), sA = 2x8 KB (16-row
// double-buffered bf16) -> 80 KB/block = exactly 2 blocks/CU -> TWO
// independent barrier domains per CU absorb r25's convoy slack (1-block/CU
// was the residual bottleneck; x re-read is L3-absorbed).
// 256 threads = 4 waves; wave w covers cols oh*128 + w*32 + {0,16}.
// Same proven mechanisms as r25: reg-staged bf16 A fill (2-deep pinned
// static sets), coalesced pack, lgkmcnt(0) + raw s_barrier per iteration,
// stores never waited, NO vmcnt / DMA / B-hoist.
// ---------------------------------------------------------------------------
__global__ __launch_bounds__(256, 2) void al_gemm(const float* __restrict__ x,
                                                  const float* __restrict__ wsrc,
                                                  const float* __restrict__ bias,
                                                  float* __restrict__ out)
{
    __shared__ char sA[2][8192];    // 16 rows x 512B bf16, chunk-XOR swizzled
    __shared__ char sB[65536];      // packed B O-half, fragment-linear

    // 512 blocks: xcd p&7 hosts a in {4k..4k+3}; 8 rowgroups x 2 O-halves.
    const int p  = blockIdx.x;
    const int q  = p >> 3;                       // 0..63
    const int a  = (p & 7) * 4 + (q & 3);
    const int b0 = ((q >> 2) & 7) * 512;
    const int oh = q >> 5;                       // O-half 0/1

    const int t    = threadIdx.x;
    const int w    = t >> 6;          // wave 0..3
    const int lane = t & 63;
    const int llo  = lane & 15, lhi = lane >> 4;

    // ---- A fill: thread t covers row t>>4, f32 cols (t&15)*16..+15
    // (4 f32x4 loads -> 8 cvt_pk -> 2 ds_write_b128 at XOR-swizzled chunks).
    const int frow = t >> 4;
    const int c0   = (t & 15) * 2;
    const float* xrow = x + ((size_t)(b0 + frow) * Asz + a) * Isz + (t & 15) * 16;
    const int wadr0 = frow * 512 + ((c0       ^ frow) << 4);
    const int wadr1 = frow * 512 + (((c0 + 1) ^ frow) << 4);
    const size_t STEP = (size_t)16 * Asz * Isz;

    f32x4 LA[4], LB[4];               // 2-deep fill pipeline (32 VGPR)

#define FISSUE(Lset, tn) {                                                     \
    const float* nx = xrow + (size_t)(tn) * STEP;                              \
    _Pragma("unroll")                                                          \
    for (int j = 0; j < 4; ++j) Lset[j] = *(const f32x4*)(nx + j * 4);         \
    asm volatile("" : "+v"(Lset[0]), "+v"(Lset[1]), "+v"(Lset[2]), "+v"(Lset[3])); }

#define FWRITE(Lset, buf) {                                                    \
    char* Ad = &sA[buf][0];                                                    \
    u32x4 pk0, pk1;                                                            \
    pk0[0] = cvtpk(Lset[0][0], Lset[0][1]); pk0[1] = cvtpk(Lset[0][2], Lset[0][3]); \
    pk0[2] = cvtpk(Lset[1][0], Lset[1][1]); pk0[3] = cvtpk(Lset[1][2], Lset[1][3]); \
    pk1[0] = cvtpk(Lset[2][0], Lset[2][1]); pk1[1] = cvtpk(Lset[2][2], Lset[2][3]); \
    pk1[2] = cvtpk(Lset[3][0], Lset[3][1]); pk1[3] = cvtpk(Lset[3][2], Lset[3][3]); \
    *(u32x4*)&Ad[wadr0] = pk0;                                                 \
    *(u32x4*)&Ad[wadr1] = pk1; }

    FISSUE(LA, 0);                    // F(0) flies during the pack

    // ---- pack this block's w[a] O-half -> sB bf16 fragment-linear (COALESCED):
    // local slot s = i*256+t covers 8 contiguous f32 at wa + s*8:
    // o_l = s>>5 (0..127), kt = (s>>2)&7, nfl = s>>9 (0..7),
    // lane_ = (o_l&15) | ((s&3)<<4). sB slot = ((kt*8+nfl)*64+lane_)*16.
    {
        const float* wa = wsrc + (size_t)a * (Osz * Isz) + (size_t)oh * 32768;
#pragma unroll
        for (int i = 0; i < 16; ++i) {
            const int s     = i * 256 + t;
            const int o_l   = s >> 5;
            const int kt    = (s >> 2) & 7;
            const int nfl   = s >> 9;
            const int lane_ = (o_l & 15) | ((s & 3) << 4);
            f32x4 lo = *(const f32x4*)(wa + (size_t)s * 8);
            f32x4 hi = *(const f32x4*)(wa + (size_t)s * 8 + 4);
            union { bf16x8 v; unsigned u[4]; } r;
            r.u[0] = cvtpk(lo[0], lo[1]); r.u[1] = cvtpk(lo[2], lo[3]);
            r.u[2] = cvtpk(hi[0], hi[1]); r.u[3] = cvtpk(hi[2], hi[3]);
            *(bf16x8*)&sB[(((kt * 8 + nfl) * 64) + lane_) * 16] = r.v;
        }
    }

    // bias in exactly 2 VGPRs (r13 invariant)
    const float bv0 = bias[a * Osz + oh * 128 + w * 32 + llo];
    const float bv1 = bias[a * Osz + oh * 128 + w * 32 + 16 + llo];

    FWRITE(LA, 0);                    // sA[0] = F(0)
    FISSUE(LB, 1);                    // F(1) flies across the sync

    __syncthreads();   // one-time full drain: sA[0] + sB visible

    auto COMPUTE_STORE = [&](const char* As, int tn) {
        f32x4 acc0 = (f32x4)(bv0), acc1 = (f32x4)(bv1);
        __builtin_amdgcn_s_setprio(1);
#pragma unroll
        for (int kt = 0; kt < 8; ++kt) {
            const bf16x8 aF  = *(const bf16x8*)&As[llo * 512 + (((kt * 4 + lhi) ^ llo) << 4)];
            const bf16x8 bF0 = *(const bf16x8*)&sB[((kt * 8 + 2 * w) * 64 + lane) * 16];
            const bf16x8 bF1 = *(const bf16x8*)&sB[((kt * 8 + 2 * w + 1) * 64 + lane) * 16];
            acc0 = __builtin_amdgcn_mfma_f32_16x16x32_bf16(aF, bF0, acc0, 0, 0, 0);
            acc1 = __builtin_amdgcn_mfma_f32_16x16x32_bf16(aF, bF1, acc1, 0, 0, 0);
        }
        __builtin_amdgcn_s_setprio(0);

        // stores: D[row = b0+tn*16+lhi*4+r2][col = oh*128 + w*32 + {0,16} + llo]
        const int trow = b0 + tn * 16 + lhi * 4;
        float* op = out + ((size_t)trow * Asz + a) * Osz + oh * 128 + w * 32 + llo;
#pragma unroll
        for (int r2 = 0; r2 < 4; ++r2) {
            op[(size_t)r2 * Asz * Osz]      = acc0[r2];
            op[(size_t)r2 * Asz * Osz + 16] = acc1[r2];
        }
    };

#pragma unroll
    for (int i = 0; i < NI / 2; ++i) {
        // ---- tn = 2i (buffer 0): LB holds F(2i+1) ----
        if (2 * i + 2 < NI) FISSUE(LA, 2 * i + 2);   // 2 phases of cover
        COMPUTE_STORE(&sA[0][0], 2 * i);
        FWRITE(LB, 1);                                // sA[1] = F(2i+1)
        asm volatile("s_waitcnt lgkmcnt(0)" ::: "memory");
        __builtin_amdgcn_s_barrier();

        // ---- tn = 2i+1 (buffer 1): LA holds F(2i+2) ----
        if (2 * i + 3 < NI) FISSUE(LB, 2 * i + 3);
        COMPUTE_STORE(&sA[1][0], 2 * i + 1);
        if (2 * i + 2 < NI) {
            FWRITE(LA, 0);                            // sA[0] = F(2i+2)
            asm volatile("s_waitcnt lgkmcnt(0)" ::: "memory");
            __builtin_amdgcn_s_barrier();
        }
    }
#undef FISSUE
#undef FWRITE
}

extern "C" void kernel_launch(void* const* d_in, const int* in_sizes, int n_in,
                              void* d_out, int out_size, void* d_ws, size_t ws_size,
                              hipStream_t stream) {
    const float* x    = (const float*)d_in[0];
    const float* w    = (const float*)d_in[1];
    const float* bias = (const float*)d_in[2];
    float* out        = (float*)d_out;
    al_gemm<<<dim3(512), dim3(256), 0, stream>>>(x, w, bias, out);
}